// Round 12
// baseline (199.097 us; speedup 1.0000x reference)
//
#include <hip/hip_runtime.h>
#include <math.h>

#define EPSF 1e-8f
#define Tn 512
#define Dn 64
#define NELEM 65536

typedef _Float16 half_t;
typedef __attribute__((ext_vector_type(4))) _Float16 half4;

__device__ __forceinline__ float sigmoidf_(float x){ return 1.0f/(1.0f+expf(-x)); }
__device__ __forceinline__ float softplusf_(float x){ return fmaxf(x,0.0f) + log1pf(expf(-fabsf(x))); }

__device__ __forceinline__ float wrs(float v){
  #pragma unroll
  for (int off=1; off<64; off<<=1) v += __shfl_xor(v, off, 64);
  return v;
}
__device__ __forceinline__ float wrm(float v){
  #pragma unroll
  for (int off=1; off<64; off<<=1) v = fmaxf(v, __shfl_xor(v, off, 64));
  return v;
}

// pnorm for one row (one full wave per row): fp32 row-major sbuf + fp16 k-major sTh
__device__ __forceinline__ void pnorm_w(float xg, int b, int r, int row, int d,
                                        float* __restrict__ sbuf_out,
                                        half_t* __restrict__ sTh_out){
  float s = softplusf_(xg);
  float sum = wrs(s);
  float p = fmaxf(s/(sum+EPSF), EPSF);
  float s2 = wrs(p);
  float sq = sqrtf(p/(s2+EPSF));
  sbuf_out[(size_t)row*Dn + d] = sq;
  sTh_out[(size_t)b*Dn*Tn + (size_t)d*Tn + r] = (half_t)sq;
}

// ---- prologue: pnorm(basin_seq) + fp16 copy (blocks 0..255) ; temps pass0 (block 256)
__global__ __launch_bounds__(256) void k_prologue(
    const float* __restrict__ basin_seq, float* __restrict__ sA, half_t* __restrict__ sThA,
    half_t* __restrict__ xhBS,
    const float* __restrict__ W_temp, const float* __restrict__ b_temp,
    const float* __restrict__ cb0, float* __restrict__ temps){
  int tid = threadIdx.x, wid = tid>>6, lane = tid&63;
  if (blockIdx.x < 256){
    int row = blockIdx.x*4 + wid;
    float xv = basin_seq[(size_t)row*Dn+lane];
    xhBS[(size_t)row*Dn+lane] = (half_t)xv;
    pnorm_w(xv, row>>9, row&511, row, lane, sA, sThA);
  } else if (tid < 64){
    float cbv = cb0[tid];
    #pragma unroll
    for (int l=0;l<4;l++){
      float v = wrs(W_temp[l*Dn + tid]*cbv);
      if (tid==0) temps[l] = sigmoidf_(v + b_temp[l]) + 0.5f;
    }
  }
}

// gate dot (NI=2): 8 threads per output d, each dots 16 of 128
__device__ __forceinline__ void gate_dot2(float (*comb)[128], float* gred,
                                          const float* __restrict__ Wfb, int tid, int lane){
  int dd = tid >> 3, k8 = tid & 7;
  const float4* wp = (const float4*)(Wfb + (size_t)dd*128 + k8*16);
  float4 w0 = wp[0], w1 = wp[1], w2 = wp[2], w3 = wp[3];
  float ga[2];
  #pragma unroll
  for (int i=0;i<2;i++){
    float4 c0 = *(const float4*)&comb[i][k8*16];
    float4 c1 = *(const float4*)&comb[i][k8*16+4];
    float4 c2 = *(const float4*)&comb[i][k8*16+8];
    float4 c3 = *(const float4*)&comb[i][k8*16+12];
    ga[i] = w0.x*c0.x + w0.y*c0.y + w0.z*c0.z + w0.w*c0.w
          + w1.x*c1.x + w1.y*c1.y + w1.z*c1.z + w1.w*c1.w
          + w2.x*c2.x + w2.y*c2.y + w2.z*c2.z + w2.w*c2.w
          + w3.x*c3.x + w3.y*c3.y + w3.z*c3.z + w3.w*c3.w;
  }
  #pragma unroll
  for (int off=1; off<8; off<<=1){
    ga[0] += __shfl_xor(ga[0],off,64); ga[1] += __shfl_xor(ga[1],off,64);
  }
  if ((lane&7)==0){ gred[dd*3+0]=ga[0]; gred[dd*3+1]=ga[1]; }
}

// ---- QFI attention, NI=2 rows/block, 512 threads, grid 512; fp16 streaming operands.
// MODE 0: pass0 mid  : write x(+fp16) + pnorm
// MODE 4: pass0 l3   : write st3 + pooled atomics + fbgate(l0) -> xg_out(+fp16) + pnorm
// MODE 5: pass1 mid  : recompute basin->temp, attn, fbgate(next) + write x(+fp16) + pnorm
// MODE 6: pass1 l3   : recompute basin->temp, attn, final residual -> out
template<int MODE>
__global__ __launch_bounds__(512) void k_attn(
    const float* __restrict__ xin, const half_t* __restrict__ xh,
    const float* __restrict__ sbuf, const half_t* __restrict__ sTh,
    const float* __restrict__ temps, const float* __restrict__ res_scale, int l,
    float* __restrict__ xout, float* __restrict__ xg_out, half_t* __restrict__ xh_out,
    float* __restrict__ sbuf_out, half_t* __restrict__ sTh_out,
    const float* __restrict__ Wfb, const float* __restrict__ bfb,
    const float* __restrict__ prev,
    const float* __restrict__ basin_seq, const float* __restrict__ rsg,
    float* __restrict__ pooled_g, const float* __restrict__ basin_coords,
    const float* __restrict__ Wc1, const float* __restrict__ bc1,
    const float* __restrict__ Wc2, const float* __restrict__ bc2,
    const float* __restrict__ Wu,  const float* __restrict__ bu,
    const float* __restrict__ W_temp, const float* __restrict__ b_temp){
  __shared__ __align__(16) union {
    float part[8*512];     // dot partials [(i*4+kq)][j]
    float pvp[32*2*64];    // PV partials [(jg*2+i)][d]
  } u;                     // 16 KB
  __shared__ __align__(8) float P[512*2];     // [j][i] exp weights
  __shared__ __align__(8) float s_i[64*2];    // [k][i]
  __shared__ float redw[2][8][2];
  __shared__ __align__(16) float comb[2][128];
  __shared__ float gred[64*3];
  __shared__ float pl[128], h1b[64], hbb[128], combb[128];
  __shared__ float tl_sh;

  int tid = threadIdx.x, wav = tid>>6, lane = tid&63;
  int row0 = blockIdx.x*2, b = row0>>9, r0 = row0&511;
  int i_ = tid>>6, d_ = lane;   // epilogue mapping for tid<128

  float xi_pre = 0.f, prev_pre = 0.f;
  if (tid < 128){
    s_i[d_*2 + i_] = sbuf[(size_t)(row0+i_)*Dn + d_];
    xi_pre = xin[(size_t)(row0+i_)*Dn + d_];
    if constexpr (MODE == 4 || MODE == 5) prev_pre = prev[(size_t)(row0+i_)*Dn + d_];
  }

  // ---- pass-1: redundant basin MLP -> temperature for this layer
  if constexpr (MODE == 5 || MODE == 6){
    if (tid < 128) pl[tid] = pooled_g[tid] * (1.0f/512.0f);
    __syncthreads();
    if (tid < 64){
      int bb=tid>>5, h=tid&31;
      float acc=0.f;
      #pragma unroll 8
      for (int d2=0; d2<64; d2++) acc += pl[bb*64+d2]*Wc1[h*64+d2];
      h1b[tid] = tanhf(acc + bc1[h]);
    }
    __syncthreads();
    if (tid < 128){
      int bb=tid>>6, dd=tid&63;
      float acc=0.f;
      #pragma unroll 8
      for (int h2=0; h2<32; h2++) acc += h1b[bb*32+h2]*Wc2[dd*32+h2];
      hbb[tid] = tanhf(acc + bc2[dd]);
    }
    __syncthreads();
    if (tid < 64){
      float agg = 0.5f*(hbb[tid] + hbb[64+tid]);
      combb[tid] = basin_coords[tid];
      combb[64+tid] = agg;
    }
    __syncthreads();
    if (tid < 64){
      float acc=0.f;
      #pragma unroll 8
      for (int k=0;k<128;k++) acc += Wu[tid*128+k]*combb[k];
      float g = sigmoidf_(acc + bu[tid]);
      float cbl = combb[tid]*(1.0f-g) + combb[64+tid]*g;
      float v = wrs(W_temp[l*Dn + tid]*cbl);
      if (tid==0) tl_sh = sigmoidf_(v + b_temp[l]) + 0.5f;
    }
  }
  __syncthreads();

  // ---- dot phase: thread (g, kq); g covers 4 j's via half4, kq a 16-k slice
  {
    int g = tid & 127, kq = tid >> 7;
    const half4* sT4 = (const half4*)(sTh + (size_t)b*Dn*Tn);  // [k][128 half4]
    float4 a0 = {0,0,0,0}, a1 = a0;
    int kb = kq*16;
    #pragma unroll
    for (int kk=0; kk<16; ++kk){
      int k = kb + kk;
      half4 vh = sT4[(size_t)k*128 + g];
      float vx=(float)vh.x, vy=(float)vh.y, vz=(float)vh.z, vw=(float)vh.w;
      float2 si = *(const float2*)&s_i[k*2];
      a0.x=fmaf(si.x,vx,a0.x); a0.y=fmaf(si.x,vy,a0.y);
      a0.z=fmaf(si.x,vz,a0.z); a0.w=fmaf(si.x,vw,a0.w);
      a1.x=fmaf(si.y,vx,a1.x); a1.y=fmaf(si.y,vy,a1.y);
      a1.z=fmaf(si.y,vz,a1.z); a1.w=fmaf(si.y,vw,a1.w);
    }
    *(float4*)&u.part[(0*4+kq)*512 + g*4] = a0;
    *(float4*)&u.part[(1*4+kq)*512 + g*4] = a1;
  }
  __syncthreads();
  // ---- combine + logits + softmax (thread j = tid)
  {
    float invT;
    if constexpr (MODE == 5 || MODE == 6) invT = 1.0f/fmaxf(tl_sh, 1e-6f);
    else invT = 1.0f/fmaxf(temps[l], 1e-6f);
    int j = tid;
    float a0 = u.part[0*512+j] + u.part[1*512+j] + u.part[2*512+j] + u.part[3*512+j];
    float a1 = u.part[4*512+j] + u.part[5*512+j] + u.part[6*512+j] + u.part[7*512+j];
    float l0 = -2.0f*acosf(fminf(fmaxf(a0,-1.0f+1e-6f),1.0f-1e-6f))*invT;
    float l1 = -2.0f*acosf(fminf(fmaxf(a1,-1.0f+1e-6f),1.0f-1e-6f))*invT;
    float m0=wrm(l0), m1=wrm(l1);
    if (lane==0){ redw[0][wav][0]=m0; redw[0][wav][1]=m1; }
    __syncthreads();
    float mv0=redw[0][0][0], mv1=redw[0][0][1];
    #pragma unroll
    for (int w=1;w<8;w++){ mv0=fmaxf(mv0,redw[0][w][0]); mv1=fmaxf(mv1,redw[0][w][1]); }
    float e0=expf(l0-mv0), e1=expf(l1-mv1);
    float2 ev = {e0,e1};
    *(float2*)&P[j*2] = ev;
    float q0=wrs(e0), q1=wrs(e1);
    if (lane==0){ redw[1][wav][0]=q0; redw[1][wav][1]=q1; }
  }
  __syncthreads();
  // ---- PV phase: thread (jg, dq); 16 j's, half4 along d
  {
    int jg = tid>>4, dq = tid&15;
    const half4* x4 = (const half4*)(xh + (size_t)b*Tn*Dn);  // [j][16 half4]
    float4 o0={0,0,0,0}, o1=o0;
    int jb = jg*16;
    #pragma unroll
    for (int jj=0; jj<16; ++jj){
      int j = jb + jj;
      half4 xvh = x4[(size_t)j*16 + dq];
      float xx=(float)xvh.x, xy=(float)xvh.y, xz=(float)xvh.z, xw=(float)xvh.w;
      float2 pw = *(const float2*)&P[j*2];
      o0.x=fmaf(pw.x,xx,o0.x); o0.y=fmaf(pw.x,xy,o0.y);
      o0.z=fmaf(pw.x,xz,o0.z); o0.w=fmaf(pw.x,xw,o0.w);
      o1.x=fmaf(pw.y,xx,o1.x); o1.y=fmaf(pw.y,xy,o1.y);
      o1.z=fmaf(pw.y,xz,o1.z); o1.w=fmaf(pw.y,xw,o1.w);
    }
    *(float4*)&u.pvp[(jg*2+0)*64 + dq*4] = o0;
    *(float4*)&u.pvp[(jg*2+1)*64 + dq*4] = o1;
  }
  __syncthreads();
  // ---- epilogue (tid<128: wave 0 = row 0, wave 1 = row 1)
  float o = 0.f;
  if (tid < 128){
    float ss = 0.f;
    #pragma unroll
    for (int jg=0; jg<32; ++jg) ss += u.pvp[(jg*2+i_)*64+d_];
    float sv = 0.f;
    #pragma unroll
    for (int w=0;w<8;w++) sv += redw[1][w][i_];
    float attn = ss/sv;
    o = xi_pre + res_scale[l]*(attn - xi_pre);
  }
  if constexpr (MODE == 0){
    if (tid < 128){
      xout[(size_t)(row0+i_)*Dn + d_] = o;
      xh_out[(size_t)(row0+i_)*Dn + d_] = (half_t)o;
      pnorm_w(o, b, r0+i_, row0+i_, d_, sbuf_out, sTh_out);
    }
  } else if constexpr (MODE == 4){
    if (tid < 128){
      xout[(size_t)(row0+i_)*Dn + d_] = o;       // st3
      atomicAdd(&pooled_g[b*64+d_], o);
      comb[i_][d_] = o;
      comb[i_][64+d_] = prev_pre;                // st0
    }
    __syncthreads();
    gate_dot2(comb, gred, Wfb, tid, lane);       // W_fb layer 0
    __syncthreads();
    if (tid < 128){
      float g = sigmoidf_(gred[d_*3+i_] + bfb[d_]);
      float xg = o*g + prev_pre*(1.0f-g);
      xg_out[(size_t)(row0+i_)*Dn + d_] = xg;
      xh_out[(size_t)(row0+i_)*Dn + d_] = (half_t)xg;
      pnorm_w(xg, b, r0+i_, row0+i_, d_, sbuf_out, sTh_out);
    }
  } else if constexpr (MODE == 5){
    if (tid < 128){
      comb[i_][d_] = o;
      comb[i_][64+d_] = prev_pre;
    }
    __syncthreads();
    gate_dot2(comb, gred, Wfb, tid, lane);
    __syncthreads();
    if (tid < 128){
      float g = sigmoidf_(gred[d_*3+i_] + bfb[d_]);
      float xg = o*g + prev_pre*(1.0f-g);
      xout[(size_t)(row0+i_)*Dn + d_] = xg;
      xh_out[(size_t)(row0+i_)*Dn + d_] = (half_t)xg;
      pnorm_w(xg, b, r0+i_, row0+i_, d_, sbuf_out, sTh_out);
    }
  } else {
    if (tid < 128){
      float c = 0.01f * rsg[0];
      xout[(size_t)(row0+i_)*Dn + d_] = o + c*(o - basin_seq[(size_t)(row0+i_)*Dn + d_]);
    }
  }
}

extern "C" void kernel_launch(void* const* d_in, const int* in_sizes, int n_in,
                              void* d_out, int out_size, void* d_ws, size_t ws_size,
                              hipStream_t stream) {
  const float* basin_seq    = (const float*)d_in[0];
  const float* basin_coords = (const float*)d_in[1];
  const float* W_temp       = (const float*)d_in[2];
  const float* b_temp       = (const float*)d_in[3];
  const float* res_scale    = (const float*)d_in[4];
  const float* W_fb         = (const float*)d_in[5];
  const float* b_fb         = (const float*)d_in[6];
  const float* Wc1          = (const float*)d_in[7];
  const float* bc1          = (const float*)d_in[8];
  const float* Wc2          = (const float*)d_in[9];
  const float* bc2          = (const float*)d_in[10];
  const float* Wu           = (const float*)d_in[11];
  const float* bu           = (const float*)d_in[12];
  const float* rsg          = (const float*)d_in[13];
  float* out = (float*)d_out;
  float* ws  = (float*)d_ws;

  const size_t N = NELEM; // 65536
  float* pooled_g = ws;             // 128 floats, zeroed by memset
  float* temps    = ws + 192;       // 4 floats
  float* base     = ws + 256;
  float* sA    = base;
  float* sB    = base + N;
  float* st0   = base + 2*N;
  float* st1   = base + 3*N;
  float* st2   = base + 4*N;
  float* st3   = base + 5*N;
  float* xA    = base + 6*N;
  float* xB    = base + 7*N;
  half_t* sThA = (half_t*)(base + 8*N);
  half_t* sThB = (half_t*)(base + 8*N + N/2);
  half_t* xhBS = (half_t*)(base + 9*N);
  half_t* xhA  = (half_t*)(base + 9*N + N/2);
  half_t* xhB  = (half_t*)(base + 10*N);

  const int GA = 512;  // NI=2 rows/block

  (void)hipMemsetAsync(d_ws, 0, 1024, stream);   // zero pooled accumulator

  // ---- pass 0
  k_prologue<<<257,256,0,stream>>>(basin_seq, sA, sThA, xhBS, W_temp, b_temp, basin_coords, temps);
  k_attn<0><<<GA,512,0,stream>>>(basin_seq, xhBS, sA, sThA, temps, res_scale, 0,
                                 st0, nullptr, xhA, sB, sThB,
                                 nullptr,nullptr,nullptr,nullptr,nullptr,
                                 nullptr,nullptr,nullptr,nullptr,nullptr,nullptr,nullptr,nullptr,nullptr,nullptr);
  k_attn<0><<<GA,512,0,stream>>>(st0, xhA, sB, sThB, temps, res_scale, 1,
                                 st1, nullptr, xhB, sA, sThA,
                                 nullptr,nullptr,nullptr,nullptr,nullptr,
                                 nullptr,nullptr,nullptr,nullptr,nullptr,nullptr,nullptr,nullptr,nullptr,nullptr);
  k_attn<0><<<GA,512,0,stream>>>(st1, xhB, sA, sThA, temps, res_scale, 2,
                                 st2, nullptr, xhA, sB, sThB,
                                 nullptr,nullptr,nullptr,nullptr,nullptr,
                                 nullptr,nullptr,nullptr,nullptr,nullptr,nullptr,nullptr,nullptr,nullptr,nullptr);
  // pass0 l3 + pooled atomics + fbgate(l0) fused
  k_attn<4><<<GA,512,0,stream>>>(st2, xhA, sB, sThB, temps, res_scale, 3,
                                 st3, xA, xhBS, sA, sThA,
                                 W_fb, b_fb, st0, nullptr,nullptr,
                                 pooled_g,nullptr,nullptr,nullptr,nullptr,nullptr,nullptr,nullptr,nullptr,nullptr);
  // ---- pass 1 (each kernel recomputes basin->temp from pooled_g)
  k_attn<5><<<GA,512,0,stream>>>(xA, xhBS, sA, sThA, nullptr, res_scale, 0,
                                 xB, nullptr, xhA, sB, sThB,
                                 W_fb + (size_t)1*Dn*2*Dn, b_fb + 1*Dn, st1, nullptr,nullptr,
                                 pooled_g, basin_coords, Wc1, bc1, Wc2, bc2, Wu, bu, W_temp, b_temp);
  k_attn<5><<<GA,512,0,stream>>>(xB, xhA, sB, sThB, nullptr, res_scale, 1,
                                 xA, nullptr, xhB, sA, sThA,
                                 W_fb + (size_t)2*Dn*2*Dn, b_fb + 2*Dn, st2, nullptr,nullptr,
                                 pooled_g, basin_coords, Wc1, bc1, Wc2, bc2, Wu, bu, W_temp, b_temp);
  k_attn<5><<<GA,512,0,stream>>>(xA, xhB, sA, sThA, nullptr, res_scale, 2,
                                 xB, nullptr, xhA, sB, sThB,
                                 W_fb + (size_t)3*Dn*2*Dn, b_fb + 3*Dn, st3, nullptr,nullptr,
                                 pooled_g, basin_coords, Wc1, bc1, Wc2, bc2, Wu, bu, W_temp, b_temp);
  k_attn<6><<<GA,512,0,stream>>>(xB, xhA, sB, sThB, nullptr, res_scale, 3,
                                 out, nullptr, nullptr, nullptr, nullptr,
                                 nullptr,nullptr,nullptr, basin_seq, rsg,
                                 pooled_g, basin_coords, Wc1, bc1, Wc2, bc2, Wu, bu, W_temp, b_temp);
}

// Round 13
// 196.088 us; speedup vs baseline: 1.0153x; 1.0153x over previous
//
#include <hip/hip_runtime.h>
#include <math.h>

#define EPSF 1e-8f
#define Tn 512
#define Dn 64
#define NELEM 65536

typedef _Float16 half_t;
typedef __attribute__((ext_vector_type(4))) _Float16 half4;

__device__ __forceinline__ float sigmoidf_(float x){ return 1.0f/(1.0f+expf(-x)); }
__device__ __forceinline__ float softplusf_(float x){ return fmaxf(x,0.0f) + log1pf(expf(-fabsf(x))); }

__device__ __forceinline__ float wrs(float v){
  #pragma unroll
  for (int off=1; off<64; off<<=1) v += __shfl_xor(v, off, 64);
  return v;
}
__device__ __forceinline__ float wrm(float v){
  #pragma unroll
  for (int off=1; off<64; off<<=1) v = fmaxf(v, __shfl_xor(v, off, 64));
  return v;
}

// pnorm for one row (one full wave per row): fp32 row-major sbuf + fp16 k-major sTh
__device__ __forceinline__ void pnorm_w(float xg, int b, int r, int row, int d,
                                        float* __restrict__ sbuf_out,
                                        half_t* __restrict__ sTh_out){
  float s = softplusf_(xg);
  float sum = wrs(s);
  float p = fmaxf(s/(sum+EPSF), EPSF);
  float s2 = wrs(p);
  float sq = sqrtf(p/(s2+EPSF));
  sbuf_out[(size_t)row*Dn + d] = sq;
  sTh_out[(size_t)b*Dn*Tn + (size_t)d*Tn + r] = (half_t)sq;
}

// ---- prologue: pnorm(basin_seq) + fp16 copy (blocks 0..255) ; temps pass0 (block 256)
__global__ __launch_bounds__(256) void k_prologue(
    const float* __restrict__ basin_seq, float* __restrict__ sA, half_t* __restrict__ sThA,
    half_t* __restrict__ xhBS,
    const float* __restrict__ W_temp, const float* __restrict__ b_temp,
    const float* __restrict__ cb0, float* __restrict__ temps){
  int tid = threadIdx.x, wid = tid>>6, lane = tid&63;
  if (blockIdx.x < 256){
    int row = blockIdx.x*4 + wid;
    float xv = basin_seq[(size_t)row*Dn+lane];
    xhBS[(size_t)row*Dn+lane] = (half_t)xv;
    pnorm_w(xv, row>>9, row&511, row, lane, sA, sThA);
  } else if (tid < 64){
    float cbv = cb0[tid];
    #pragma unroll
    for (int l=0;l<4;l++){
      float v = wrs(W_temp[l*Dn + tid]*cbv);
      if (tid==0) temps[l] = sigmoidf_(v + b_temp[l]) + 0.5f;
    }
  }
}

// gate dot (NI=2): 8 threads per output d, each dots 16 of 128
__device__ __forceinline__ void gate_dot2(float (*comb)[128], float* gred,
                                          const float* __restrict__ Wfb, int tid, int lane){
  int dd = tid >> 3, k8 = tid & 7;
  const float4* wp = (const float4*)(Wfb + (size_t)dd*128 + k8*16);
  float4 w0 = wp[0], w1 = wp[1], w2 = wp[2], w3 = wp[3];
  float ga[2];
  #pragma unroll
  for (int i=0;i<2;i++){
    float4 c0 = *(const float4*)&comb[i][k8*16];
    float4 c1 = *(const float4*)&comb[i][k8*16+4];
    float4 c2 = *(const float4*)&comb[i][k8*16+8];
    float4 c3 = *(const float4*)&comb[i][k8*16+12];
    ga[i] = w0.x*c0.x + w0.y*c0.y + w0.z*c0.z + w0.w*c0.w
          + w1.x*c1.x + w1.y*c1.y + w1.z*c1.z + w1.w*c1.w
          + w2.x*c2.x + w2.y*c2.y + w2.z*c2.z + w2.w*c2.w
          + w3.x*c3.x + w3.y*c3.y + w3.z*c3.z + w3.w*c3.w;
  }
  #pragma unroll
  for (int off=1; off<8; off<<=1){
    ga[0] += __shfl_xor(ga[0],off,64); ga[1] += __shfl_xor(ga[1],off,64);
  }
  if ((lane&7)==0){ gred[dd*3+0]=ga[0]; gred[dd*3+1]=ga[1]; }
}

// ---- QFI attention, NI=2 rows/block, 512 threads, grid 512; fp16 streaming operands.
// MODE 0: pass0 mid : write x(+fp16) + pnorm
// MODE 4: pass0 l3  : write st3 + pooled atomics + fbgate(l0) -> xg(+fp16) + pnorm;
//                     last finishing block computes basin MLP -> temps1 (all 4 layers)
// MODE 2: pass1 mid : fbgate(next) + write x(+fp16) + pnorm
// MODE 3: pass1 l3  : final residual -> out
template<int MODE>
__global__ __launch_bounds__(512) void k_attn(
    const float* __restrict__ xin, const half_t* __restrict__ xh,
    const float* __restrict__ sbuf, const half_t* __restrict__ sTh,
    const float* __restrict__ temps, const float* __restrict__ res_scale, int l,
    float* __restrict__ xout, float* __restrict__ xg_out, half_t* __restrict__ xh_out,
    float* __restrict__ sbuf_out, half_t* __restrict__ sTh_out,
    const float* __restrict__ Wfb, const float* __restrict__ bfb,
    const float* __restrict__ prev,
    const float* __restrict__ basin_seq, const float* __restrict__ rsg,
    float* __restrict__ pooled_g, unsigned* __restrict__ cnt,
    float* __restrict__ temps_out, const float* __restrict__ basin_coords,
    const float* __restrict__ Wc1, const float* __restrict__ bc1,
    const float* __restrict__ Wc2, const float* __restrict__ bc2,
    const float* __restrict__ Wu,  const float* __restrict__ bu,
    const float* __restrict__ W_temp, const float* __restrict__ b_temp){
  __shared__ __align__(16) union {
    float part[8*512];     // dot partials [(i*4+kq)][j]
    float pvp[32*2*64];    // PV partials [(jg*2+i)][d]
  } u;                     // 16 KB
  __shared__ __align__(8) float P[512*2];     // [j][i] exp weights
  __shared__ __align__(8) float s_i[64*2];    // [k][i]
  __shared__ float redw[2][8][2];
  __shared__ __align__(16) float comb[2][128];
  __shared__ float gred[64*3];
  __shared__ float pl[128], h1b[64], hbb[128], combb[128];
  __shared__ bool lastf;

  int tid = threadIdx.x, wav = tid>>6, lane = tid&63;
  int row0 = blockIdx.x*2, b = row0>>9, r0 = row0&511;
  int i_ = tid>>6, d_ = lane;   // epilogue mapping for tid<128

  float xi_pre = 0.f, prev_pre = 0.f;
  if (tid < 128){
    s_i[d_*2 + i_] = sbuf[(size_t)(row0+i_)*Dn + d_];
    xi_pre = xin[(size_t)(row0+i_)*Dn + d_];
    if constexpr (MODE == 4 || MODE == 2) prev_pre = prev[(size_t)(row0+i_)*Dn + d_];
  }
  __syncthreads();

  float invT = 1.0f/fmaxf(temps[l], 1e-6f);
  // ---- dot phase: thread (g, kq); g covers 4 j's via half4, kq a 16-k slice
  {
    int g = tid & 127, kq = tid >> 7;
    const half4* sT4 = (const half4*)(sTh + (size_t)b*Dn*Tn);  // [k][128 half4]
    float4 a0 = {0,0,0,0}, a1 = a0;
    int kb = kq*16;
    #pragma unroll
    for (int kk=0; kk<16; ++kk){
      int k = kb + kk;
      half4 vh = sT4[(size_t)k*128 + g];
      float vx=(float)vh.x, vy=(float)vh.y, vz=(float)vh.z, vw=(float)vh.w;
      float2 si = *(const float2*)&s_i[k*2];
      a0.x=fmaf(si.x,vx,a0.x); a0.y=fmaf(si.x,vy,a0.y);
      a0.z=fmaf(si.x,vz,a0.z); a0.w=fmaf(si.x,vw,a0.w);
      a1.x=fmaf(si.y,vx,a1.x); a1.y=fmaf(si.y,vy,a1.y);
      a1.z=fmaf(si.y,vz,a1.z); a1.w=fmaf(si.y,vw,a1.w);
    }
    *(float4*)&u.part[(0*4+kq)*512 + g*4] = a0;
    *(float4*)&u.part[(1*4+kq)*512 + g*4] = a1;
  }
  __syncthreads();
  // ---- combine + logits + softmax (thread j = tid)
  {
    int j = tid;
    float a0 = u.part[0*512+j] + u.part[1*512+j] + u.part[2*512+j] + u.part[3*512+j];
    float a1 = u.part[4*512+j] + u.part[5*512+j] + u.part[6*512+j] + u.part[7*512+j];
    float l0 = -2.0f*acosf(fminf(fmaxf(a0,-1.0f+1e-6f),1.0f-1e-6f))*invT;
    float l1 = -2.0f*acosf(fminf(fmaxf(a1,-1.0f+1e-6f),1.0f-1e-6f))*invT;
    float m0=wrm(l0), m1=wrm(l1);
    if (lane==0){ redw[0][wav][0]=m0; redw[0][wav][1]=m1; }
    __syncthreads();
    float mv0=redw[0][0][0], mv1=redw[0][0][1];
    #pragma unroll
    for (int w=1;w<8;w++){ mv0=fmaxf(mv0,redw[0][w][0]); mv1=fmaxf(mv1,redw[0][w][1]); }
    float e0=expf(l0-mv0), e1=expf(l1-mv1);
    float2 ev = {e0,e1};
    *(float2*)&P[j*2] = ev;
    float q0=wrs(e0), q1=wrs(e1);
    if (lane==0){ redw[1][wav][0]=q0; redw[1][wav][1]=q1; }
  }
  __syncthreads();
  // ---- PV phase: thread (jg, dq); 16 j's, half4 along d
  {
    int jg = tid>>4, dq = tid&15;
    const half4* x4 = (const half4*)(xh + (size_t)b*Tn*Dn);  // [j][16 half4]
    float4 o0={0,0,0,0}, o1=o0;
    int jb = jg*16;
    #pragma unroll
    for (int jj=0; jj<16; ++jj){
      int j = jb + jj;
      half4 xvh = x4[(size_t)j*16 + dq];
      float xx=(float)xvh.x, xy=(float)xvh.y, xz=(float)xvh.z, xw=(float)xvh.w;
      float2 pw = *(const float2*)&P[j*2];
      o0.x=fmaf(pw.x,xx,o0.x); o0.y=fmaf(pw.x,xy,o0.y);
      o0.z=fmaf(pw.x,xz,o0.z); o0.w=fmaf(pw.x,xw,o0.w);
      o1.x=fmaf(pw.y,xx,o1.x); o1.y=fmaf(pw.y,xy,o1.y);
      o1.z=fmaf(pw.y,xz,o1.z); o1.w=fmaf(pw.y,xw,o1.w);
    }
    *(float4*)&u.pvp[(jg*2+0)*64 + dq*4] = o0;
    *(float4*)&u.pvp[(jg*2+1)*64 + dq*4] = o1;
  }
  __syncthreads();
  // ---- epilogue (tid<128: wave 0 = row 0, wave 1 = row 1)
  float o = 0.f;
  if (tid < 128){
    float ss = 0.f;
    #pragma unroll
    for (int jg=0; jg<32; ++jg) ss += u.pvp[(jg*2+i_)*64+d_];
    float sv = 0.f;
    #pragma unroll
    for (int w=0;w<8;w++) sv += redw[1][w][i_];
    float attn = ss/sv;
    o = xi_pre + res_scale[l]*(attn - xi_pre);
  }
  if constexpr (MODE == 0){
    if (tid < 128){
      xout[(size_t)(row0+i_)*Dn + d_] = o;
      xh_out[(size_t)(row0+i_)*Dn + d_] = (half_t)o;
      pnorm_w(o, b, r0+i_, row0+i_, d_, sbuf_out, sTh_out);
    }
  } else if constexpr (MODE == 4){
    if (tid < 128){
      xout[(size_t)(row0+i_)*Dn + d_] = o;       // st3
      atomicAdd(&pooled_g[b*64+d_], o);
      comb[i_][d_] = o;
      comb[i_][64+d_] = prev_pre;                // st0
    }
    __syncthreads();
    gate_dot2(comb, gred, Wfb, tid, lane);       // W_fb layer 0
    __syncthreads();
    if (tid < 128){
      float g = sigmoidf_(gred[d_*3+i_] + bfb[d_]);
      float xg = o*g + prev_pre*(1.0f-g);
      xg_out[(size_t)(row0+i_)*Dn + d_] = xg;
      xh_out[(size_t)(row0+i_)*Dn + d_] = (half_t)xg;
      pnorm_w(xg, b, r0+i_, row0+i_, d_, sbuf_out, sTh_out);
    }
    // ---- last-finishing block computes basin MLP -> temps1 (no other block waits)
    __syncthreads();
    if (tid == 0){
      __threadfence();
      unsigned old = atomicAdd(cnt, 1u);
      lastf = (old == gridDim.x - 1);
    }
    __syncthreads();
    if (lastf){
      if (tid < 128)
        pl[tid] = __hip_atomic_load(&pooled_g[tid], __ATOMIC_RELAXED, __HIP_MEMORY_SCOPE_AGENT) * (1.0f/512.0f);
      __syncthreads();
      if (tid < 64){
        int bb=tid>>5, h=tid&31;
        float acc=0.f;
        #pragma unroll 8
        for (int d2=0; d2<64; d2++) acc += pl[bb*64+d2]*Wc1[h*64+d2];
        h1b[tid] = tanhf(acc + bc1[h]);
      }
      __syncthreads();
      if (tid < 128){
        int bb=tid>>6, dd=tid&63;
        float acc=0.f;
        #pragma unroll 8
        for (int h2=0; h2<32; h2++) acc += h1b[bb*32+h2]*Wc2[dd*32+h2];
        hbb[tid] = tanhf(acc + bc2[dd]);
      }
      __syncthreads();
      if (tid < 64){
        float agg = 0.5f*(hbb[tid] + hbb[64+tid]);
        combb[tid] = basin_coords[tid];
        combb[64+tid] = agg;
      }
      __syncthreads();
      if (tid < 64){
        float acc=0.f;
        #pragma unroll 8
        for (int k=0;k<128;k++) acc += Wu[tid*128+k]*combb[k];
        float g = sigmoidf_(acc + bu[tid]);
        float cbl = combb[tid]*(1.0f-g) + combb[64+tid]*g;
        #pragma unroll
        for (int ll=0; ll<4; ll++){
          float v = wrs(W_temp[ll*Dn + tid]*cbl);
          if (tid==0) temps_out[ll] = sigmoidf_(v + b_temp[ll]) + 0.5f;
        }
      }
    }
  } else if constexpr (MODE == 2){
    if (tid < 128){
      comb[i_][d_] = o;
      comb[i_][64+d_] = prev_pre;
    }
    __syncthreads();
    gate_dot2(comb, gred, Wfb, tid, lane);
    __syncthreads();
    if (tid < 128){
      float g = sigmoidf_(gred[d_*3+i_] + bfb[d_]);
      float xg = o*g + prev_pre*(1.0f-g);
      xout[(size_t)(row0+i_)*Dn + d_] = xg;
      xh_out[(size_t)(row0+i_)*Dn + d_] = (half_t)xg;
      pnorm_w(xg, b, r0+i_, row0+i_, d_, sbuf_out, sTh_out);
    }
  } else {
    if (tid < 128){
      float c = 0.01f * rsg[0];
      xout[(size_t)(row0+i_)*Dn + d_] = o + c*(o - basin_seq[(size_t)(row0+i_)*Dn + d_]);
    }
  }
}

extern "C" void kernel_launch(void* const* d_in, const int* in_sizes, int n_in,
                              void* d_out, int out_size, void* d_ws, size_t ws_size,
                              hipStream_t stream) {
  const float* basin_seq    = (const float*)d_in[0];
  const float* basin_coords = (const float*)d_in[1];
  const float* W_temp       = (const float*)d_in[2];
  const float* b_temp       = (const float*)d_in[3];
  const float* res_scale    = (const float*)d_in[4];
  const float* W_fb         = (const float*)d_in[5];
  const float* b_fb         = (const float*)d_in[6];
  const float* Wc1          = (const float*)d_in[7];
  const float* bc1          = (const float*)d_in[8];
  const float* Wc2          = (const float*)d_in[9];
  const float* bc2          = (const float*)d_in[10];
  const float* Wu           = (const float*)d_in[11];
  const float* bu           = (const float*)d_in[12];
  const float* rsg          = (const float*)d_in[13];
  float* out = (float*)d_out;
  float* ws  = (float*)d_ws;

  const size_t N = NELEM; // 65536
  float* pooled_g = ws;                     // 128 floats (zeroed)
  unsigned* cnt   = (unsigned*)(ws + 160);  // 1 uint (zeroed)
  float* temps0   = ws + 192;               // 4 floats (prologue)
  float* temps1   = ws + 224;               // 4 floats (MODE-4 last block)
  float* base     = ws + 256;
  float* sA    = base;
  float* sB    = base + N;
  float* st0   = base + 2*N;
  float* st1   = base + 3*N;
  float* st2   = base + 4*N;
  float* st3   = base + 5*N;
  float* xA    = base + 6*N;
  float* xB    = base + 7*N;
  half_t* sThA = (half_t*)(base + 8*N);
  half_t* sThB = (half_t*)(base + 8*N + N/2);
  half_t* xhBS = (half_t*)(base + 9*N);
  half_t* xhA  = (half_t*)(base + 9*N + N/2);
  half_t* xhB  = (half_t*)(base + 10*N);

  const int GA = 512;  // NI=2 rows/block

  (void)hipMemsetAsync(d_ws, 0, 1024, stream);   // zero pooled + counter

  // ---- pass 0
  k_prologue<<<257,256,0,stream>>>(basin_seq, sA, sThA, xhBS, W_temp, b_temp, basin_coords, temps0);
  k_attn<0><<<GA,512,0,stream>>>(basin_seq, xhBS, sA, sThA, temps0, res_scale, 0,
                                 st0, nullptr, xhA, sB, sThB,
                                 nullptr,nullptr,nullptr,nullptr,nullptr,
                                 nullptr,nullptr,nullptr,nullptr,nullptr,nullptr,nullptr,nullptr,nullptr,nullptr,nullptr,nullptr);
  k_attn<0><<<GA,512,0,stream>>>(st0, xhA, sB, sThB, temps0, res_scale, 1,
                                 st1, nullptr, xhB, sA, sThA,
                                 nullptr,nullptr,nullptr,nullptr,nullptr,
                                 nullptr,nullptr,nullptr,nullptr,nullptr,nullptr,nullptr,nullptr,nullptr,nullptr,nullptr,nullptr);
  k_attn<0><<<GA,512,0,stream>>>(st1, xhB, sA, sThA, temps0, res_scale, 2,
                                 st2, nullptr, xhA, sB, sThB,
                                 nullptr,nullptr,nullptr,nullptr,nullptr,
                                 nullptr,nullptr,nullptr,nullptr,nullptr,nullptr,nullptr,nullptr,nullptr,nullptr,nullptr,nullptr);
  // pass0 l3 + pooled + fbgate(l0) + last-block basin->temps1
  k_attn<4><<<GA,512,0,stream>>>(st2, xhA, sB, sThB, temps0, res_scale, 3,
                                 st3, xA, xhBS, sA, sThA,
                                 W_fb, b_fb, st0, nullptr,nullptr,
                                 pooled_g, cnt, temps1, basin_coords,
                                 Wc1, bc1, Wc2, bc2, Wu, bu, W_temp, b_temp);
  // ---- pass 1
  k_attn<2><<<GA,512,0,stream>>>(xA, xhBS, sA, sThA, temps1, res_scale, 0,
                                 xB, nullptr, xhA, sB, sThB,
                                 W_fb + (size_t)1*Dn*2*Dn, b_fb + 1*Dn, st1, nullptr,nullptr,
                                 nullptr,nullptr,nullptr,nullptr,nullptr,nullptr,nullptr,nullptr,nullptr,nullptr,nullptr,nullptr);
  k_attn<2><<<GA,512,0,stream>>>(xB, xhA, sB, sThB, temps1, res_scale, 1,
                                 xA, nullptr, xhB, sA, sThA,
                                 W_fb + (size_t)2*Dn*2*Dn, b_fb + 2*Dn, st2, nullptr,nullptr,
                                 nullptr,nullptr,nullptr,nullptr,nullptr,nullptr,nullptr,nullptr,nullptr,nullptr,nullptr,nullptr);
  k_attn<2><<<GA,512,0,stream>>>(xA, xhB, sA, sThA, temps1, res_scale, 2,
                                 xB, nullptr, xhA, sB, sThB,
                                 W_fb + (size_t)3*Dn*2*Dn, b_fb + 3*Dn, st3, nullptr,nullptr,
                                 nullptr,nullptr,nullptr,nullptr,nullptr,nullptr,nullptr,nullptr,nullptr,nullptr,nullptr,nullptr);
  k_attn<3><<<GA,512,0,stream>>>(xB, xhA, sB, sThB, temps1, res_scale, 3,
                                 out, nullptr, nullptr, nullptr, nullptr,
                                 nullptr,nullptr,nullptr, basin_seq, rsg,
                                 nullptr,nullptr,nullptr,nullptr,nullptr,nullptr,nullptr,nullptr,nullptr,nullptr,nullptr,nullptr);
}

// Round 14
// 175.044 us; speedup vs baseline: 1.1374x; 1.1202x over previous
//
#include <hip/hip_runtime.h>
#include <math.h>

#define EPSF 1e-8f
#define Tn 512
#define Dn 64
#define ROWS 1024
#define NELEM 65536

typedef _Float16 half_t;
typedef __attribute__((ext_vector_type(4))) _Float16 half4;

__device__ __forceinline__ float sigmoidf_(float x){ return 1.0f/(1.0f+expf(-x)); }
__device__ __forceinline__ float softplusf_(float x){ return fmaxf(x,0.0f) + log1pf(expf(-fabsf(x))); }

__device__ __forceinline__ float wrs(float v){
  #pragma unroll
  for (int off=1; off<64; off<<=1) v += __shfl_xor(v, off, 64);
  return v;
}
__device__ __forceinline__ float wrm(float v){
  #pragma unroll
  for (int off=1; off<64; off<<=1) v = fmaxf(v, __shfl_xor(v, off, 64));
  return v;
}

// pnorm for one row (one full wave per row): fp32 row-major sbuf + fp16 k-major sTh
__device__ __forceinline__ void pnorm_w(float xg, int b, int r, int row, int d,
                                        float* __restrict__ sbuf_out,
                                        half_t* __restrict__ sTh_out){
  float s = softplusf_(xg);
  float sum = wrs(s);
  float p = fmaxf(s/(sum+EPSF), EPSF);
  float s2 = wrs(p);
  float sq = sqrtf(p/(s2+EPSF));
  sbuf_out[(size_t)row*Dn + d] = sq;
  sTh_out[(size_t)b*Dn*Tn + (size_t)d*Tn + r] = (half_t)sq;
}

// ---- prologue: pnorm(basin_seq) + fp16 copy (blocks 0..255) ; temps (block 256)
__global__ __launch_bounds__(256) void k_prologue(
    const float* __restrict__ basin_seq, float* __restrict__ sA, half_t* __restrict__ sThA,
    half_t* __restrict__ xhBS,
    const float* __restrict__ W_temp, const float* __restrict__ b_temp,
    const float* __restrict__ cb0, float* __restrict__ temps){
  int tid = threadIdx.x, wid = tid>>6, lane = tid&63;
  if (blockIdx.x < 256){
    int row = blockIdx.x*4 + wid;
    float xv = basin_seq[(size_t)row*Dn+lane];
    xhBS[(size_t)row*Dn+lane] = (half_t)xv;
    pnorm_w(xv, row>>9, row&511, row, lane, sA, sThA);
  } else if (tid < 64){
    float cbv = cb0[tid];
    #pragma unroll
    for (int l=0;l<4;l++){
      float v = wrs(W_temp[l*Dn + tid]*cbv);
      if (tid==0) temps[l] = sigmoidf_(v + b_temp[l]) + 0.5f;
    }
  }
}

// gate dot (NI=2): 8 threads per output d, each dots 16 of 128
__device__ __forceinline__ void gate_dot2(float (*comb)[128], float* gred,
                                          const float* __restrict__ Wfb, int tid, int lane){
  int dd = tid >> 3, k8 = tid & 7;
  const float4* wp = (const float4*)(Wfb + (size_t)dd*128 + k8*16);
  float4 w0 = wp[0], w1 = wp[1], w2 = wp[2], w3 = wp[3];
  float ga[2];
  #pragma unroll
  for (int i=0;i<2;i++){
    float4 c0 = *(const float4*)&comb[i][k8*16];
    float4 c1 = *(const float4*)&comb[i][k8*16+4];
    float4 c2 = *(const float4*)&comb[i][k8*16+8];
    float4 c3 = *(const float4*)&comb[i][k8*16+12];
    ga[i] = w0.x*c0.x + w0.y*c0.y + w0.z*c0.z + w0.w*c0.w
          + w1.x*c1.x + w1.y*c1.y + w1.z*c1.z + w1.w*c1.w
          + w2.x*c2.x + w2.y*c2.y + w2.z*c2.z + w2.w*c2.w
          + w3.x*c3.x + w3.y*c3.y + w3.z*c3.z + w3.w*c3.w;
  }
  #pragma unroll
  for (int off=1; off<8; off<<=1){
    ga[0] += __shfl_xor(ga[0],off,64); ga[1] += __shfl_xor(ga[1],off,64);
  }
  if ((lane&7)==0){ gred[dd*3+0]=ga[0]; gred[dd*3+1]=ga[1]; }
}

// ---- QFI attention, NI=2 rows/block, 512 threads, grid 512; fp16 streaming operands.
// MODE 0: write x(+fp16) + pnorm ; 1: write x only (pre-basin)
// MODE 2: fbgate(next layer) + write x(+fp16) + pnorm ; 3: final residual -> out
template<int MODE>
__global__ __launch_bounds__(512) void k_attn(
    const float* __restrict__ xin, const half_t* __restrict__ xh,
    const float* __restrict__ sbuf, const half_t* __restrict__ sTh,
    const float* __restrict__ temps, const float* __restrict__ res_scale, int l,
    float* __restrict__ xout, half_t* __restrict__ xh_out,
    float* __restrict__ sbuf_out, half_t* __restrict__ sTh_out,
    const float* __restrict__ Wfb, const float* __restrict__ bfb,
    const float* __restrict__ prev,
    const float* __restrict__ basin_seq, const float* __restrict__ rsg){
  __shared__ __align__(16) union {
    float part[8*512];     // dot partials [(i*4+kq)][j]
    float pvp[32*2*64];    // PV partials [(jg*2+i)][d]
  } u;                     // 16 KB
  __shared__ __align__(8) float P[512*2];     // [j][i] exp weights
  __shared__ __align__(8) float s_i[64*2];    // [k][i]
  __shared__ float redw[2][8][2];
  __shared__ __align__(16) float comb[2][128];
  __shared__ float gred[64*3];

  int tid = threadIdx.x, wav = tid>>6, lane = tid&63;
  int row0 = blockIdx.x*2, b = row0>>9, r0 = row0&511;
  int i_ = tid>>6, d_ = lane;   // epilogue mapping for tid<128

  float xi_pre = 0.f, prev_pre = 0.f;
  if (tid < 128){
    s_i[d_*2 + i_] = sbuf[(size_t)(row0+i_)*Dn + d_];
    xi_pre = xin[(size_t)(row0+i_)*Dn + d_];
    if constexpr (MODE == 2) prev_pre = prev[(size_t)(row0+i_)*Dn + d_];
  }
  __syncthreads();

  float invT = 1.0f/fmaxf(temps[l], 1e-6f);
  // ---- dot phase: thread (g, kq); g covers 4 j's via half4, kq a 16-k slice
  {
    int g = tid & 127, kq = tid >> 7;
    const half4* sT4 = (const half4*)(sTh + (size_t)b*Dn*Tn);  // [k][128 half4]
    float4 a0 = {0,0,0,0}, a1 = a0;
    int kb = kq*16;
    #pragma unroll
    for (int kk=0; kk<16; ++kk){
      int k = kb + kk;
      half4 vh = sT4[(size_t)k*128 + g];
      float vx=(float)vh.x, vy=(float)vh.y, vz=(float)vh.z, vw=(float)vh.w;
      float2 si = *(const float2*)&s_i[k*2];
      a0.x=fmaf(si.x,vx,a0.x); a0.y=fmaf(si.x,vy,a0.y);
      a0.z=fmaf(si.x,vz,a0.z); a0.w=fmaf(si.x,vw,a0.w);
      a1.x=fmaf(si.y,vx,a1.x); a1.y=fmaf(si.y,vy,a1.y);
      a1.z=fmaf(si.y,vz,a1.z); a1.w=fmaf(si.y,vw,a1.w);
    }
    *(float4*)&u.part[(0*4+kq)*512 + g*4] = a0;
    *(float4*)&u.part[(1*4+kq)*512 + g*4] = a1;
  }
  __syncthreads();
  // ---- combine + logits + softmax (thread j = tid)
  {
    int j = tid;
    float a0 = u.part[0*512+j] + u.part[1*512+j] + u.part[2*512+j] + u.part[3*512+j];
    float a1 = u.part[4*512+j] + u.part[5*512+j] + u.part[6*512+j] + u.part[7*512+j];
    float l0 = -2.0f*acosf(fminf(fmaxf(a0,-1.0f+1e-6f),1.0f-1e-6f))*invT;
    float l1 = -2.0f*acosf(fminf(fmaxf(a1,-1.0f+1e-6f),1.0f-1e-6f))*invT;
    float m0=wrm(l0), m1=wrm(l1);
    if (lane==0){ redw[0][wav][0]=m0; redw[0][wav][1]=m1; }
    __syncthreads();
    float mv0=redw[0][0][0], mv1=redw[0][0][1];
    #pragma unroll
    for (int w=1;w<8;w++){ mv0=fmaxf(mv0,redw[0][w][0]); mv1=fmaxf(mv1,redw[0][w][1]); }
    float e0=expf(l0-mv0), e1=expf(l1-mv1);
    float2 ev = {e0,e1};
    *(float2*)&P[j*2] = ev;
    float q0=wrs(e0), q1=wrs(e1);
    if (lane==0){ redw[1][wav][0]=q0; redw[1][wav][1]=q1; }
  }
  __syncthreads();
  // ---- PV phase: thread (jg, dq); 16 j's, half4 along d
  {
    int jg = tid>>4, dq = tid&15;
    const half4* x4 = (const half4*)(xh + (size_t)b*Tn*Dn);  // [j][16 half4]
    float4 o0={0,0,0,0}, o1=o0;
    int jb = jg*16;
    #pragma unroll
    for (int jj=0; jj<16; ++jj){
      int j = jb + jj;
      half4 xvh = x4[(size_t)j*16 + dq];
      float xx=(float)xvh.x, xy=(float)xvh.y, xz=(float)xvh.z, xw=(float)xvh.w;
      float2 pw = *(const float2*)&P[j*2];
      o0.x=fmaf(pw.x,xx,o0.x); o0.y=fmaf(pw.x,xy,o0.y);
      o0.z=fmaf(pw.x,xz,o0.z); o0.w=fmaf(pw.x,xw,o0.w);
      o1.x=fmaf(pw.y,xx,o1.x); o1.y=fmaf(pw.y,xy,o1.y);
      o1.z=fmaf(pw.y,xz,o1.z); o1.w=fmaf(pw.y,xw,o1.w);
    }
    *(float4*)&u.pvp[(jg*2+0)*64 + dq*4] = o0;
    *(float4*)&u.pvp[(jg*2+1)*64 + dq*4] = o1;
  }
  __syncthreads();
  // ---- epilogue (tid<128: wave 0 = row 0, wave 1 = row 1)
  float o = 0.f;
  if (tid < 128){
    float ss = 0.f;
    #pragma unroll
    for (int jg=0; jg<32; ++jg) ss += u.pvp[(jg*2+i_)*64+d_];
    float sv = 0.f;
    #pragma unroll
    for (int w=0;w<8;w++) sv += redw[1][w][i_];
    float attn = ss/sv;
    o = xi_pre + res_scale[l]*(attn - xi_pre);
  }
  if constexpr (MODE == 0){
    if (tid < 128){
      xout[(size_t)(row0+i_)*Dn + d_] = o;
      xh_out[(size_t)(row0+i_)*Dn + d_] = (half_t)o;
      pnorm_w(o, b, r0+i_, row0+i_, d_, sbuf_out, sTh_out);
    }
  } else if constexpr (MODE == 1){
    if (tid < 128) xout[(size_t)(row0+i_)*Dn + d_] = o;
  } else if constexpr (MODE == 2){
    if (tid < 128){
      comb[i_][d_] = o;
      comb[i_][64+d_] = prev_pre;
    }
    __syncthreads();
    gate_dot2(comb, gred, Wfb, tid, lane);
    __syncthreads();
    if (tid < 128){
      float g = sigmoidf_(gred[d_*3+i_] + bfb[d_]);
      float xg = o*g + prev_pre*(1.0f-g);
      xout[(size_t)(row0+i_)*Dn + d_] = xg;
      xh_out[(size_t)(row0+i_)*Dn + d_] = (half_t)xg;
      pnorm_w(xg, b, r0+i_, row0+i_, d_, sbuf_out, sTh_out);
    }
  } else {
    if (tid < 128){
      float c = 0.01f * rsg[0];
      xout[(size_t)(row0+i_)*Dn + d_] = o + c*(o - basin_seq[(size_t)(row0+i_)*Dn + d_]);
    }
  }
}

// ---- blocks 0..255: pass-1 layer-0 fbgate + pnorm (4 rows); block 256: basin+temps
__global__ __launch_bounds__(256) void k_basinprep(
    const float* __restrict__ st3, const float* __restrict__ st0,
    const float* __restrict__ W_fb, const float* __restrict__ b_fb,
    float* __restrict__ xA, half_t* __restrict__ xhA,
    float* __restrict__ sA, half_t* __restrict__ sThA,
    const float* __restrict__ Wc1, const float* __restrict__ bc1,
    const float* __restrict__ Wc2, const float* __restrict__ bc2,
    const float* __restrict__ Wu,  const float* __restrict__ bu,
    const float* __restrict__ cb_in, float* __restrict__ cb_out,
    const float* __restrict__ W_temp, const float* __restrict__ b_temp,
    float* __restrict__ temps){
  int tid = threadIdx.x, wid = tid>>6, lane = tid&63;
  __shared__ __align__(16) float comb4[4][128];
  __shared__ float pooled[128];
  __shared__ float h1[64];
  __shared__ float hb[128];
  __shared__ float combb[128];
  if (blockIdx.x < 256){
    int row = blockIdx.x*4 + wid;
    float xv = st3[(size_t)row*Dn+lane];
    float pvv = st0[(size_t)row*Dn+lane];
    comb4[wid][lane] = xv; comb4[wid][64+lane] = pvv;
    __syncthreads();
    const float4* W  = (const float4*)(W_fb + (size_t)lane*128);   // l = 0
    const float4* c4 = (const float4*)comb4[wid];
    float g0=0.f,g1=0.f;
    #pragma unroll
    for (int k=0;k<32;k+=2){
      float4 w0=W[k],   c0=c4[k];
      float4 w1=W[k+1], c1=c4[k+1];
      g0 += w0.x*c0.x + w0.y*c0.y + w0.z*c0.z + w0.w*c0.w;
      g1 += w1.x*c1.x + w1.y*c1.y + w1.z*c1.z + w1.w*c1.w;
    }
    float g = sigmoidf_(g0+g1 + b_fb[lane]);
    float xg = xv*g + pvv*(1.0f-g);
    xA[(size_t)row*Dn+lane] = xg;
    xhA[(size_t)row*Dn+lane] = (half_t)xg;
    pnorm_w(xg, row>>9, row&511, row, lane, sA, sThA);
  } else {
    if (tid < 128){
      int b = tid >> 6, d = tid & 63;
      float acc=0.f;
      const float* xb = st3 + (size_t)b*Tn*Dn + d;
      for (int t=0;t<Tn;t++) acc += xb[(size_t)t*Dn];
      pooled[tid] = acc * (1.0f/Tn);
    }
    __syncthreads();
    if (tid < 64){
      int b = tid >> 5, h = tid & 31;
      float acc=0.f;
      #pragma unroll 8
      for (int d2=0; d2<64; d2++) acc += pooled[b*64+d2]*Wc1[h*64+d2];
      h1[tid] = tanhf(acc + bc1[h]);
    }
    __syncthreads();
    if (tid < 128){
      int b = tid >> 6, d = tid & 63;
      float acc=0.f;
      #pragma unroll 8
      for (int h2=0; h2<32; h2++) acc += h1[b*32+h2]*Wc2[d*32+h2];
      hb[tid] = tanhf(acc + bc2[d]);
    }
    __syncthreads();
    if (tid < 64){
      float agg = 0.5f*(hb[tid] + hb[64+tid]);
      combb[tid] = cb_in[tid];
      combb[64+tid] = agg;
    }
    __syncthreads();
    if (tid < 64){
      float acc=0.f;
      #pragma unroll 8
      for (int k=0;k<128;k++) acc += Wu[tid*128+k]*combb[k];
      float g = sigmoidf_(acc + bu[tid]);
      float nb = combb[tid]*(1.0f-g) + combb[64+tid]*g;
      cb_out[tid] = nb;
      #pragma unroll
      for (int l=0;l<4;l++){
        float v = wrs(W_temp[l*Dn + tid]*nb);
        if (tid==0) temps[l] = sigmoidf_(v + b_temp[l]) + 0.5f;
      }
    }
  }
}

extern "C" void kernel_launch(void* const* d_in, const int* in_sizes, int n_in,
                              void* d_out, int out_size, void* d_ws, size_t ws_size,
                              hipStream_t stream) {
  const float* basin_seq    = (const float*)d_in[0];
  const float* basin_coords = (const float*)d_in[1];
  const float* W_temp       = (const float*)d_in[2];
  const float* b_temp       = (const float*)d_in[3];
  const float* res_scale    = (const float*)d_in[4];
  const float* W_fb         = (const float*)d_in[5];
  const float* b_fb         = (const float*)d_in[6];
  const float* Wc1          = (const float*)d_in[7];
  const float* bc1          = (const float*)d_in[8];
  const float* Wc2          = (const float*)d_in[9];
  const float* bc2          = (const float*)d_in[10];
  const float* Wu           = (const float*)d_in[11];
  const float* bu           = (const float*)d_in[12];
  const float* rsg          = (const float*)d_in[13];
  float* out = (float*)d_out;
  float* ws  = (float*)d_ws;

  const size_t N = NELEM; // 65536
  float* sA    = ws;
  float* sB    = ws + N;
  float* st    = ws + 2*N;          // st0..st3 : 4*N
  float* xA    = ws + 6*N;
  float* xB    = ws + 7*N;
  half_t* sThA = (half_t*)(ws + 8*N);
  half_t* sThB = (half_t*)(ws + 8*N + N/2);
  half_t* xhBS = (half_t*)(ws + 9*N);
  half_t* xhA  = (half_t*)(ws + 9*N + N/2);
  half_t* xhB  = (half_t*)(ws + 10*N);
  float* temps = ws + 10*N + N/2;
  float* cb    = ws + 10*N + N/2 + 64;
  float* st0 = st, *st1 = st+N, *st2 = st+2*N, *st3 = st+3*N;

  const int GA = 512;  // NI=2 rows/block

  // ---- pass 0
  k_prologue<<<257,256,0,stream>>>(basin_seq, sA, sThA, xhBS, W_temp, b_temp, basin_coords, temps);
  k_attn<0><<<GA,512,0,stream>>>(basin_seq, xhBS, sA, sThA, temps, res_scale, 0,
                                 st0, xhA, sB, sThB, nullptr,nullptr,nullptr,nullptr,nullptr);
  k_attn<0><<<GA,512,0,stream>>>(st0, xhA, sB, sThB, temps, res_scale, 1,
                                 st1, xhB, sA, sThA, nullptr,nullptr,nullptr,nullptr,nullptr);
  k_attn<0><<<GA,512,0,stream>>>(st1, xhB, sA, sThA, temps, res_scale, 2,
                                 st2, xhA, sB, sThB, nullptr,nullptr,nullptr,nullptr,nullptr);
  k_attn<1><<<GA,512,0,stream>>>(st2, xhA, sB, sThB, temps, res_scale, 3,
                                 st3, nullptr, nullptr, nullptr, nullptr,nullptr,nullptr,nullptr,nullptr);
  // ---- basin update + pass-1 layer-0 prep
  k_basinprep<<<257,256,0,stream>>>(st3, st0, W_fb, b_fb, xA, xhA, sA, sThA,
                                    Wc1, bc1, Wc2, bc2, Wu, bu,
                                    basin_coords, cb, W_temp, b_temp, temps);
  // ---- pass 1
  k_attn<2><<<GA,512,0,stream>>>(xA, xhA, sA, sThA, temps, res_scale, 0,
                                 xB, xhB, sB, sThB,
                                 W_fb + (size_t)1*Dn*2*Dn, b_fb + 1*Dn, st1, nullptr,nullptr);
  k_attn<2><<<GA,512,0,stream>>>(xB, xhB, sB, sThB, temps, res_scale, 1,
                                 xA, xhA, sA, sThA,
                                 W_fb + (size_t)2*Dn*2*Dn, b_fb + 2*Dn, st2, nullptr,nullptr);
  k_attn<2><<<GA,512,0,stream>>>(xA, xhA, sA, sThA, temps, res_scale, 2,
                                 xB, xhB, sB, sThB,
                                 W_fb + (size_t)3*Dn*2*Dn, b_fb + 3*Dn, st3, nullptr,nullptr);
  k_attn<3><<<GA,512,0,stream>>>(xB, xhB, sB, sThB, temps, res_scale, 3,
                                 out, nullptr, nullptr, nullptr,
                                 nullptr,nullptr,nullptr, basin_seq, rsg);
}